// Round 8
// baseline (462.184 us; speedup 1.0000x reference)
//
#include <hip/hip_runtime.h>

// B=8, NQ=1024, NC=4096, D=256, C+1=25. FP32 I/O; labels int32.
// All-fp16 MFMA pipeline. R8: attn 256thr q-tile64, sA dbuf + sB sbuf
// (53KB -> 3 blk/CU), l via ones-column MFMA, mask prefetch; emb pipeline
// barrier fix (loads issued after barrier so they drain at the NEXT one).

typedef __attribute__((ext_vector_type(8))) _Float16 half8;
typedef __attribute__((ext_vector_type(4))) float floatx4;

#define WB 8
#define WNQ 1024
#define WNC 4096
#define NROWS 8192          // B*NQ

static __device__ __forceinline__ float logsig(float x) {
    return (x >= 0.f) ? -log1pf(__expf(-x)) : x - log1pf(__expf(x));
}

union V16h { int4 v; half8 h8; _Float16 h[8]; unsigned short s[8]; uint2 u2[2]; };
union F8   { float4 v[2]; float f[8]; };
union H4   { _Float16 h[4]; uint2 u; unsigned short s[4]; };

static __device__ __forceinline__ void async_lds16(const _Float16* g, _Float16* l) {
    __builtin_amdgcn_global_load_lds(
        (const __attribute__((address_space(1))) unsigned int*)g,
        (__attribute__((address_space(3))) unsigned int*)l,
        16, 0, 0);
}

// ---------------------------------------------------------------------------
// wprep: WT fp16 [256 n][512 k] = W_rel^T; GenB fp16 [32 n][256 k].
// ---------------------------------------------------------------------------
__global__ void wprep_kernel(const float* __restrict__ Wrel,
                             const float* __restrict__ Wgen,
                             const float* __restrict__ Wcp,
                             _Float16* __restrict__ WT,
                             _Float16* __restrict__ GenB)
{
    const int bx = blockIdx.x;
    if (bx < 256) {
        const int n = bx;
        for (int k = threadIdx.x; k < 512; k += 256)
            WT[(long)n * 512 + k] = (_Float16)Wrel[(long)k * 256 + n];
    } else {
        const int n = bx - 256;
        const int k = threadIdx.x;
        float v = 0.f;
        if (n < 25)       v = Wgen[(long)k * 25 + n];
        else if (n == 25) v = Wcp[k];
        GenB[(long)n * 256 + k] = (_Float16)v;
    }
}

// ---------------------------------------------------------------------------
// emb: concat(head,tail) @ W_rel + b_rel -> fp16 (+ transposed CfT for c).
// Block = 64m x 256n, 4 waves. Pipeline: stage A(ks) -> barrier -> issue
// A/W(ks+1) (drain at next barrier, full compute of cover) -> MFMA(ks).
// CfT epilogue via swizzled LDS bounce -> 16B coalesced stores.
// ---------------------------------------------------------------------------
__global__ __launch_bounds__(256, 3) void emb_kernel(
    const float* __restrict__ q_head, const float* __restrict__ q_tail,
    const float* __restrict__ c_head, const float* __restrict__ c_tail,
    const _Float16* __restrict__ WT,
    const float* __restrict__ brel,
    _Float16* __restrict__ Qf, _Float16* __restrict__ Cf,
    _Float16* __restrict__ CfT)
{
    __shared__ _Float16 sA[2][2048];   // 8 KB dbuf A-tile fp16
    __shared__ _Float16 sO[256 * 64];  // 32 KB out tile [n][8B-slot ^ (n&15)]

    const int tid  = threadIdx.x;
    const int lane = tid & 63;
    const int wv   = tid >> 6;
    const int l15  = lane & 15;
    const int quad = lane >> 4;
    const int n0   = wv * 64;

    const float* head; const float* tail; _Float16* Ef;
    long m0; bool isQ;
    if (blockIdx.x < 128) {
        isQ = true;  head = q_head; tail = q_tail; Ef = Qf;
        m0 = (long)blockIdx.x * 64;
    } else {
        isQ = false; head = c_head; tail = c_tail; Ef = Cf;
        m0 = (long)(blockIdx.x - 128) * 64;
    }

    const long arow = m0 + (tid >> 2);
    const int  akc  = (tid & 3) * 8;

    floatx4 acc[4][4];
#pragma unroll
    for (int a = 0; a < 4; ++a)
#pragma unroll
        for (int bq = 0; bq < 4; ++bq) acc[a][bq] = (floatx4)(0.0f);

    F8 aCur;
    aCur.v[0] = *(const float4*)(head + arow * 256 + akc);
    aCur.v[1] = *(const float4*)(head + arow * 256 + akc + 4);
    V16h wCur[4];
#pragma unroll
    for (int nt = 0; nt < 4; ++nt)
        wCur[nt].v = *(const int4*)(WT + (long)(n0 + nt * 16 + l15) * 512 + quad * 8);

    for (int ks = 0; ks < 16; ++ks) {
        {
            V16h hp;
#pragma unroll
            for (int i = 0; i < 8; ++i) hp.h[i] = (_Float16)aCur.f[i];
            *(int4*)&sA[ks & 1][tid * 8] = hp.v;
        }
        __syncthreads();                 // drains LDS write AND last iter's loads

        F8 aNxt; V16h wNxt[4];
        if (ks < 15) {                   // issued AFTER barrier -> drain next iter
            const int kg = (ks + 1) * 32;
            const float* srcb = (kg < 256) ? (head + kg) : (tail + (kg - 256));
            aNxt.v[0] = *(const float4*)(srcb + arow * 256 + akc);
            aNxt.v[1] = *(const float4*)(srcb + arow * 256 + akc + 4);
#pragma unroll
            for (int nt = 0; nt < 4; ++nt)
                wNxt[nt].v = *(const int4*)(WT + (long)(n0 + nt * 16 + l15) * 512 + kg + quad * 8);
        } else {
            aNxt = aCur;
#pragma unroll
            for (int nt = 0; nt < 4; ++nt) wNxt[nt] = wCur[nt];
        }

        V16h af[4];
#pragma unroll
        for (int mb = 0; mb < 4; ++mb)
            af[mb].v = *(const int4*)&sA[ks & 1][(mb * 16 + l15) * 32 + quad * 8];
#pragma unroll
        for (int mb = 0; mb < 4; ++mb)
#pragma unroll
            for (int nt = 0; nt < 4; ++nt)
                acc[mb][nt] = __builtin_amdgcn_mfma_f32_16x16x32_f16(af[mb].h8, wCur[nt].h8, acc[mb][nt], 0, 0, 0);

        aCur = aNxt;
#pragma unroll
        for (int nt = 0; nt < 4; ++nt) wCur[nt] = wNxt[nt];
    }

    float bias[4];
#pragma unroll
    for (int nt = 0; nt < 4; ++nt) bias[nt] = brel[n0 + nt * 16 + l15];

#pragma unroll
    for (int mb = 0; mb < 4; ++mb)
#pragma unroll
        for (int nt = 0; nt < 4; ++nt) {
            H4 hq;
#pragma unroll
            for (int r = 0; r < 4; ++r) {
                const long row = m0 + mb * 16 + quad * 4 + r;
                const _Float16 h = (_Float16)(acc[mb][nt][r] + bias[nt]);
                Ef[row * 256 + n0 + nt * 16 + l15] = h;
                hq.h[r] = h;
            }
            if (!isQ) {
                const int n  = n0 + nt * 16 + l15;
                const int sw = (mb * 4 + quad) ^ l15;
                *(uint2*)&sO[n * 64 + sw * 4] = hq.u;
            }
        }

    if (!isQ) {
        __syncthreads();
        const int bidx = (int)(m0 >> 12);
        const int jc0  = (int)(m0 & 4095);
        const int c    = tid & 7;
        const int nl   = tid >> 3;
#pragma unroll
        for (int i = 0; i < 8; ++i) {
            const int n  = nl + 32 * i;
            const int s0 = (2 * c)     ^ (n & 15);
            const int s1 = (2 * c + 1) ^ (n & 15);
            const uint2 u0 = *(const uint2*)&sO[n * 64 + s0 * 4];
            const uint2 u1 = *(const uint2*)&sO[n * 64 + s1 * 4];
            int4 out; out.x = u0.x; out.y = u0.y; out.z = u1.x; out.w = u1.y;
            *(int4*)&CfT[(long)bidx * 1048576 + (long)n * 4096 + jc0 + c * 8] = out;
        }
    }
}

// ---------------------------------------------------------------------------
// gen head: genlog[8192][32] = q_emb @ [Wgen | Wcp_q] (+bgen).
// ---------------------------------------------------------------------------
__global__ __launch_bounds__(256, 4) void gen_kernel(
    const _Float16* __restrict__ Qf,
    const _Float16* __restrict__ GenB,
    const float* __restrict__ bgen,
    float* __restrict__ genlog)
{
    const int tid  = threadIdx.x;
    const int lane = tid & 63;
    const int wv   = tid >> 6;
    const int l15  = lane & 15;
    const int quad = lane >> 4;
    const long m0  = (long)blockIdx.x * 64 + wv * 16;

    floatx4 acc[2];
    acc[0] = (floatx4)(0.0f); acc[1] = (floatx4)(0.0f);
#pragma unroll
    for (int ks = 0; ks < 8; ++ks) {
        V16h a, b0, b1;
        a.v  = *(const int4*)(Qf + (m0 + l15) * 256 + ks * 32 + quad * 8);
        b0.v = *(const int4*)(GenB + (long)(l15)      * 256 + ks * 32 + quad * 8);
        b1.v = *(const int4*)(GenB + (long)(16 + l15) * 256 + ks * 32 + quad * 8);
        acc[0] = __builtin_amdgcn_mfma_f32_16x16x32_f16(a.h8, b0.h8, acc[0], 0, 0, 0);
        acc[1] = __builtin_amdgcn_mfma_f32_16x16x32_f16(a.h8, b1.h8, acc[1], 0, 0, 0);
    }
#pragma unroll
    for (int nt = 0; nt < 2; ++nt) {
        const int col = nt * 16 + l15;
        const float bias = (col < 25) ? bgen[col] : 0.f;
#pragma unroll
        for (int r = 0; r < 4; ++r)
            genlog[(m0 + quad * 4 + r) * 32 + col] = acc[nt][r] + bias;
    }
}

// ---------------------------------------------------------------------------
// Fused flash attention + grouped class sums. 256 thr, q-tile 64, j-tile 32.
// grid 16qt*8b*ns XCD-swizzled. sA dbuf / sB sbuf (53 KB -> 3 blk/CU):
//   barrier1 -> stageB(cur)+mask-prefetch -> S/softmax -> barrier2 ->
//   stageA(next) + PV.
// l_run computed by MFMA ones-column (B col 31 == 1) -> no sum shuffles.
// ---------------------------------------------------------------------------
__global__ __launch_bounds__(256, 3) void attn_kernel(
    const _Float16* __restrict__ qf,
    const _Float16* __restrict__ cf,
    const _Float16* __restrict__ cfT,
    const int*      __restrict__ labels,
    const float*    __restrict__ maskp,
    unsigned short* __restrict__ Oh,    // fp16 [ns*8192][288]
    float* __restrict__ Mst,
    float* __restrict__ Lst,
    int jtiles, int nsh)
{
    __shared__ _Float16 sA[2][8192];    // 32 KB natural c tile (dbuf)
    __shared__ _Float16 sB[8192];       // 16 KB transposed c tile (sbuf)
    __shared__ _Float16 Pw[4][16 * 40]; //  5 KB per-wave P

    const int tid  = threadIdx.x;
    const int lane = tid & 63;
    const int wv   = tid >> 6;
    const int l15  = lane & 15;
    const int quad = lane >> 4;

    const int f   = blockIdx.x;
    const int xcd = f & 7;
    const int seq = f >> 3;
    const int qt  = seq & 15;
    const int u   = seq >> 4;
    const int pr  = u * 8 + xcd;
    const int b   = pr >> nsh;
    const int sp  = pr & ((1 << nsh) - 1);
    const int q0  = qt * 64;

    V16h qfr[8];
    {
        const long qrow = (long)b * WNQ + q0 + wv * 16 + l15;
#pragma unroll
        for (int ks = 0; ks < 8; ++ks)
            qfr[ks].v = *(const int4*)(qf + qrow * 256 + ks * 32 + quad * 8);
    }

    floatx4 O[18];
#pragma unroll
    for (int i = 0; i < 18; ++i) O[i] = (floatx4)(0.0f);
    float m_run = -INFINITY;

    const int jb0 = sp * (jtiles * 32);

    auto stageA = [&](int bf, int jb) {
        const long cbase = ((long)b * WNC + jb) * 256;
#pragma unroll
        for (int t = 0; t < 4; ++t) {
            const int idx = wv * 4 + t;            // 0..15
            const int ks = idx >> 1, jh = idx & 1;
            async_lds16(cf + cbase + (jh * 16 + l15) * 256 + ks * 32 + quad * 8,
                        &sA[bf][idx * 512]);
        }
    };
    auto stageB = [&](int jb) {
        const long tbase = (long)b * 1048576 + jb;
#pragma unroll
        for (int t = 0; t < 4; ++t) {
            const int W = wv * 4 + t;              // d-block 0..15
            async_lds16(cfT + tbase + (long)(W * 16 + (lane >> 2)) * 4096 + (lane & 3) * 8,
                        &sB[W * 512]);
        }
    };

    stageA(0, jb0);
    // mask prefetch for it=0
    float4 mv0c = *(const float4*)(maskp + (long)b * WNC + jb0 + quad * 4);
    float4 mv1c = *(const float4*)(maskp + (long)b * WNC + jb0 + 16 + quad * 4);

    for (int it = 0; it < jtiles; ++it) {
        const int cur = it & 1;
        const int jb  = jb0 + it * 32;
        __syncthreads();                       // barrier1: sA[cur] ready
        stageB(jb);

        // prefetch next mask; load labels for this iter (used late, in PV)
        const int jbn = (it + 1 < jtiles) ? jb + 32 : jb;
        const float4 mv0n = *(const float4*)(maskp + (long)b * WNC + jbn + quad * 4);
        const float4 mv1n = *(const float4*)(maskp + (long)b * WNC + jbn + 16 + quad * 4);
        const int4 lb0 = *(const int4*)(labels + (long)b * WNC + jb + quad * 8);
        const int4 lb1 = *(const int4*)(labels + (long)b * WNC + jb + quad * 8 + 4);

        // ---- S^T = c (A from sA) . q^T (B regs) ----
        floatx4 accS0 = (floatx4)(0.0f), accS1 = (floatx4)(0.0f);
#pragma unroll
        for (int ks = 0; ks < 8; ++ks) {
            V16h a0, a1;
            a0.v = *(const int4*)&sA[cur][(ks * 2 + 0) * 512 + (quad * 16 + l15) * 8];
            a1.v = *(const int4*)&sA[cur][(ks * 2 + 1) * 512 + (quad * 16 + l15) * 8];
            accS0 = __builtin_amdgcn_mfma_f32_16x16x32_f16(a0.h8, qfr[ks].h8, accS0, 0, 0, 0);
            accS1 = __builtin_amdgcn_mfma_f32_16x16x32_f16(a1.h8, qfr[ks].h8, accS1, 0, 0, 0);
        }
        const float* mv0p = (const float*)&mv0c;
        const float* mv1p = (const float*)&mv1c;
#pragma unroll
        for (int r = 0; r < 4; ++r) {
            accS0[r] *= mv0p[r];
            accS1[r] *= mv1p[r];
        }

        // ---- online max per q = lane&15 (sum handled by ones-column MFMA) ----
        float v = fmaxf(fmaxf(fmaxf(accS0[0], accS0[1]), fmaxf(accS0[2], accS0[3])),
                        fmaxf(fmaxf(accS1[0], accS1[1]), fmaxf(accS1[2], accS1[3])));
        v = fmaxf(v, __shfl_xor(v, 16, 64));
        v = fmaxf(v, __shfl_xor(v, 32, 64));
        const float m_new = fmaxf(m_run, v);
        const bool upd = __any(m_new > m_run);
        const float alpha = __expf(m_run - m_new);
        float p[8];
#pragma unroll
        for (int r = 0; r < 4; ++r) {
            p[r]     = __expf(accS0[r] - m_new);
            p[4 + r] = __expf(accS1[r] - m_new);
        }
        m_run = m_new;

        if (upd) {
            float ar[4];
#pragma unroll
            for (int r = 0; r < 4; ++r) ar[r] = __shfl(alpha, quad * 4 + r, 64);
#pragma unroll
            for (int fo = 0; fo < 18; ++fo)
#pragma unroll
                for (int r = 0; r < 4; ++r) O[fo][r] *= ar[r];
        }

        // ---- P -> per-wave LDS (A layout [q][j]) ----
#pragma unroll
        for (int jf = 0; jf < 2; ++jf) {
            H4 w;
#pragma unroll
            for (int r = 0; r < 4; ++r) w.h[r] = (_Float16)p[jf * 4 + r];
            *(uint2*)&Pw[wv][l15 * 40 + jf * 16 + quad * 4] = w.u;
        }
        asm volatile("" ::: "memory");
        V16h pf;
        pf.v = *(const int4*)&Pw[wv][l15 * 40 + quad * 8];

        const int* lbp0 = (const int*)&lb0;
        const int* lbp1 = (const int*)&lb1;
        V16h oh0, oh1;
#pragma unroll
        for (int i = 0; i < 8; ++i) {
            const int lv = (i < 4) ? lbp0[i] : lbp1[i - 4];
            oh0.h[i] = (lv == l15)        ? (_Float16)1.0f : (_Float16)0.0f;
            // col 31 (l15==15) is the all-ones column: accumulates l in O[17]
            oh1.h[i] = (lv == (l15 + 16) || l15 == 15) ? (_Float16)1.0f : (_Float16)0.0f;
        }

        __syncthreads();                       // barrier2: sB ready
        if (it + 1 < jtiles) stageA(cur ^ 1, jb + 32);

        // ---- O += P @ [c | onehot+ones] (B from sB) ----
#pragma unroll
        for (int dt = 0; dt < 16; ++dt) {
            V16h bfr;
            bfr.v = *(const int4*)&sB[((dt * 16 + l15) * 4 + quad) * 8];
            O[dt] = __builtin_amdgcn_mfma_f32_16x16x32_f16(pf.h8, bfr.h8, O[dt], 0, 0, 0);
        }
        O[16] = __builtin_amdgcn_mfma_f32_16x16x32_f16(pf.h8, oh0.h8, O[16], 0, 0, 0);
        O[17] = __builtin_amdgcn_mfma_f32_16x16x32_f16(pf.h8, oh1.h8, O[17], 0, 0, 0);

        mv0c = mv0n; mv1c = mv1n;
    }

    {
        const long base = (long)(sp * WB + b) * WNQ + q0 + wv * 16;
#pragma unroll
        for (int dt = 0; dt < 18; ++dt)
#pragma unroll
            for (int r = 0; r < 4; ++r) {
                H4 h; h.h[0] = (_Float16)O[dt][r];
                Oh[(base + quad * 4 + r) * 288 + dt * 16 + l15] = h.s[0];
            }
        if (lane < 16) Mst[base + lane] = m_run;
        if (l15 == 15) {
#pragma unroll
            for (int r = 0; r < 4; ++r)
                Lst[base + quad * 4 + r] = O[17][r];   // ones-column = l
        }
    }
}

// ---------------------------------------------------------------------------
// Combine splits + log_softmax(gen) + gate + logaddexp. 4 rows per block.
// ---------------------------------------------------------------------------
__global__ __launch_bounds__(256) void final_kernel(
    const float* __restrict__ genlog,
    const unsigned short* __restrict__ Oh,
    const float* __restrict__ Mst,
    const float* __restrict__ Lst,
    const float* __restrict__ Wcp,
    const float* __restrict__ bcp,
    float* __restrict__ outp,
    int ns)
{
    __shared__ float gA[4][32];
    __shared__ float cdA[4][32];

    const int tid  = threadIdx.x;
    const int lane = tid & 63;
    const int wv   = tid >> 6;
    const int row  = blockIdx.x * 4 + wv;

    float ms[8];
#pragma unroll
    for (int s = 0; s < 8; ++s) ms[s] = (s < ns) ? Mst[(long)s * NROWS + row] : -INFINITY;
    float mstar = -INFINITY;
#pragma unroll
    for (int s = 0; s < 8; ++s) mstar = fmaxf(mstar, ms[s]);
    float wgt[8]; float L = 0.f;
#pragma unroll
    for (int s = 0; s < 8; ++s) {
        wgt[s] = (ms[s] == -INFINITY) ? 0.f : __expf(ms[s] - mstar);
        if (s < ns) L += Lst[(long)s * NROWS + row] * wgt[s];
    }

    const int d0 = lane * 4;
    float ctx[4] = {0.f, 0.f, 0.f, 0.f};
#pragma unroll
    for (int s = 0; s < 8; ++s) {
        if (s < ns) {
            H4 t; t.u = *(const uint2*)&Oh[((long)s * NROWS + row) * 288 + d0];
#pragma unroll
            for (int i = 0; i < 4; ++i) ctx[i] += wgt[s] * (float)t.h[i];
        }
    }

    float cls[4] = {0.f, 0.f, 0.f, 0.f};
    if (lane < 8) {
#pragma unroll
        for (int s = 0; s < 8; ++s) {
            if (s < ns) {
                H4 t; t.u = *(const uint2*)&Oh[((long)s * NROWS + row) * 288 + 256 + lane * 4];
#pragma unroll
                for (int i = 0; i < 4; ++i) cls[i] += wgt[s] * (float)t.h[i];
            }
        }
    }

    float g = (lane < 25) ? genlog[(long)row * 32 + lane] : -INFINITY;
    float mg = g;
#pragma unroll
    for (int off = 32; off >= 1; off >>= 1) mg = fmaxf(mg, __shfl_xor(mg, off, 64));
    float se = (lane < 25) ? __expf(g - mg) : 0.f;
#pragma unroll
    for (int off = 32; off >= 1; off >>= 1) se += __shfl_xor(se, off, 64);
    const float glsm = g - mg - logf(se);

    const float qgate = genlog[(long)row * 32 + 25];
    const float invL = 1.f / L;
    float part = 0.f;
#pragma unroll
    for (int i = 0; i < 4; ++i)
        part += ctx[i] * invL * Wcp[256 + d0 + i];
#pragma unroll
    for (int off = 32; off >= 1; off >>= 1) part += __shfl_xor(part, off, 64);
    const float logit = qgate + part + bcp[0];

    const float lscp  = logsig(logit);
    const float lsgen = logsig(-logit);
    const float logL  = logf(L);

    if (lane < 8) {
#pragma unroll
        for (int i = 0; i < 4; ++i)
            cdA[wv][lane * 4 + i] = (cls[i] > 0.f) ? (logf(cls[i]) - logL) : -INFINITY;
    }
    if (lane < 25) gA[wv][lane] = glsm;
    __syncthreads();

    if (lane < 25) {
        const float a  = lscp + cdA[wv][lane];
        const float bb = lsgen + gA[wv][lane];
        const float mx = fmaxf(a, bb);
        const float o  = (mx == -INFINITY) ? -INFINITY
                         : mx + log1pf(__expf(fminf(a, bb) - mx));
        outp[(long)row * 25 + lane] = o;
    }
}

// ---------------------------------------------------------------------------
extern "C" void kernel_launch(void* const* d_in, const int* in_sizes, int n_in,
                              void* d_out, int out_size, void* d_ws, size_t ws_size,
                              hipStream_t stream) {
    const float* q_head = (const float*)d_in[0];
    const float* q_tail = (const float*)d_in[1];
    const float* c_head = (const float*)d_in[2];
    const float* c_tail = (const float*)d_in[3];
    const int*   labels = (const int*)d_in[4];
    const float* maskp  = (const float*)d_in[5];
    const float* Wrel   = (const float*)d_in[6];
    const float* brel   = (const float*)d_in[7];
    const float* Wgen   = (const float*)d_in[8];
    const float* bgen   = (const float*)d_in[9];
    const float* Wcp    = (const float*)d_in[10];
    const float* bcp    = (const float*)d_in[11];

    auto need = [](long ns) -> long { return 39075840l + ns * 4784128l; };
    int ns = 8, nsh = 3;
    if ((long)ws_size < need(8)) { ns = 4; nsh = 2; }
    if ((long)ws_size < need(4)) { ns = 2; nsh = 1; }
    if ((long)ws_size < need(2)) { ns = 1; nsh = 0; }
    const int jtiles = 128 / ns;

    char* ws = (char*)d_ws;
    _Float16* Qf     = (_Float16*)(ws);                   //  4 MB
    _Float16* Cf     = (_Float16*)(ws + 4194304l);        // 16 MB
    _Float16* CfT    = (_Float16*)(ws + 20971520l);       // 16 MB
    _Float16* WT     = (_Float16*)(ws + 37748736l);       // 256 KB
    _Float16* GenB   = (_Float16*)(ws + 38010880l);       // 16 KB
    float*    genlog = (float*)   (ws + 38027264l);       //  1 MB
    unsigned short* Oh = (unsigned short*)(ws + 39075840l);  // ns*4.5 MB fp16
    float*    Mst    = (float*)   (ws + 39075840l + (long)ns * 4718592l);
    float*    Lst    = Mst + (long)ns * NROWS;

    hipLaunchKernelGGL(wprep_kernel, dim3(288), dim3(256), 0, stream,
                       Wrel, Wgen, Wcp, WT, GenB);
    hipLaunchKernelGGL(emb_kernel, dim3(640), dim3(256), 0, stream,
                       q_head, q_tail, c_head, c_tail, WT, brel, Qf, Cf, CfT);
    hipLaunchKernelGGL(gen_kernel, dim3(128), dim3(256), 0, stream,
                       Qf, GenB, bgen, genlog);
    hipLaunchKernelGGL(attn_kernel, dim3(16 * 8 * ns), dim3(256), 0, stream,
                       Qf, Cf, CfT, labels, maskp, Oh, Mst, Lst, jtiles, nsh);
    hipLaunchKernelGGL(final_kernel, dim3(NROWS / 4), dim3(256), 0, stream,
                       genlog, Oh, Mst, Lst, Wcp, bcp, (float*)d_out, ns);
}

// Round 9
// 267.227 us; speedup vs baseline: 1.7296x; 1.7296x over previous
//
#include <hip/hip_runtime.h>

// B=8, NQ=1024, NC=4096, D=256, C+1=25. FP32 I/O; labels int32.
// All-fp16 MFMA pipeline. R9: attn = R6 proven structure (dbuf, single
// barrier, bounds(256,2) -- NO register squeeze) + mask/label prefetch +
// alpha-skip. emb = fixed software pipeline (issue-after-barrier).

typedef __attribute__((ext_vector_type(8))) _Float16 half8;
typedef __attribute__((ext_vector_type(4))) float floatx4;

#define WB 8
#define WNQ 1024
#define WNC 4096
#define NROWS 8192          // B*NQ

static __device__ __forceinline__ float logsig(float x) {
    return (x >= 0.f) ? -log1pf(__expf(-x)) : x - log1pf(__expf(x));
}

union V16h { int4 v; half8 h8; _Float16 h[8]; unsigned short s[8]; uint2 u2[2]; };
union F8   { float4 v[2]; float f[8]; };
union H4   { _Float16 h[4]; uint2 u; unsigned short s[4]; };

static __device__ __forceinline__ void async_lds16(const _Float16* g, _Float16* l) {
    __builtin_amdgcn_global_load_lds(
        (const __attribute__((address_space(1))) unsigned int*)g,
        (__attribute__((address_space(3))) unsigned int*)l,
        16, 0, 0);
}

// ---------------------------------------------------------------------------
// wprep: WT fp16 [256 n][512 k] = W_rel^T; GenB fp16 [32 n][256 k].
// ---------------------------------------------------------------------------
__global__ void wprep_kernel(const float* __restrict__ Wrel,
                             const float* __restrict__ Wgen,
                             const float* __restrict__ Wcp,
                             _Float16* __restrict__ WT,
                             _Float16* __restrict__ GenB)
{
    const int bx = blockIdx.x;
    if (bx < 256) {
        const int n = bx;
        for (int k = threadIdx.x; k < 512; k += 256)
            WT[(long)n * 512 + k] = (_Float16)Wrel[(long)k * 256 + n];
    } else {
        const int n = bx - 256;
        const int k = threadIdx.x;
        float v = 0.f;
        if (n < 25)       v = Wgen[(long)k * 25 + n];
        else if (n == 25) v = Wcp[k];
        GenB[(long)n * 256 + k] = (_Float16)v;
    }
}

// ---------------------------------------------------------------------------
// emb: concat(head,tail) @ W_rel + b_rel -> fp16 (+ transposed CfT for c).
// Block = 64m x 256n, 4 waves. Pipeline: stage A(ks) -> barrier -> issue
// A/W(ks+1) (drains at NEXT barrier, covered by full compute) -> MFMA(ks).
// CfT epilogue via swizzled LDS bounce -> 16B coalesced stores.
// bounds(256,2): register budget 256, no spill risk (~140 live).
// ---------------------------------------------------------------------------
__global__ __launch_bounds__(256, 2) void emb_kernel(
    const float* __restrict__ q_head, const float* __restrict__ q_tail,
    const float* __restrict__ c_head, const float* __restrict__ c_tail,
    const _Float16* __restrict__ WT,
    const float* __restrict__ brel,
    _Float16* __restrict__ Qf, _Float16* __restrict__ Cf,
    _Float16* __restrict__ CfT)
{
    __shared__ _Float16 sA[2][2048];   // 8 KB dbuf A-tile fp16
    __shared__ _Float16 sO[256 * 64];  // 32 KB out tile [n][8B-slot ^ (n&15)]

    const int tid  = threadIdx.x;
    const int lane = tid & 63;
    const int wv   = tid >> 6;
    const int l15  = lane & 15;
    const int quad = lane >> 4;
    const int n0   = wv * 64;

    const float* head; const float* tail; _Float16* Ef;
    long m0; bool isQ;
    if (blockIdx.x < 128) {
        isQ = true;  head = q_head; tail = q_tail; Ef = Qf;
        m0 = (long)blockIdx.x * 64;
    } else {
        isQ = false; head = c_head; tail = c_tail; Ef = Cf;
        m0 = (long)(blockIdx.x - 128) * 64;
    }

    const long arow = m0 + (tid >> 2);
    const int  akc  = (tid & 3) * 8;

    floatx4 acc[4][4];
#pragma unroll
    for (int a = 0; a < 4; ++a)
#pragma unroll
        for (int bq = 0; bq < 4; ++bq) acc[a][bq] = (floatx4)(0.0f);

    F8 aCur;
    aCur.v[0] = *(const float4*)(head + arow * 256 + akc);
    aCur.v[1] = *(const float4*)(head + arow * 256 + akc + 4);
    V16h wCur[4];
#pragma unroll
    for (int nt = 0; nt < 4; ++nt)
        wCur[nt].v = *(const int4*)(WT + (long)(n0 + nt * 16 + l15) * 512 + quad * 8);

    for (int ks = 0; ks < 16; ++ks) {
        {
            V16h hp;
#pragma unroll
            for (int i = 0; i < 8; ++i) hp.h[i] = (_Float16)aCur.f[i];
            *(int4*)&sA[ks & 1][tid * 8] = hp.v;
        }
        __syncthreads();                 // drains LDS write AND last iter's loads

        F8 aNxt; V16h wNxt[4];
        if (ks < 15) {                   // issued AFTER barrier -> drain next iter
            const int kg = (ks + 1) * 32;
            const float* srcb = (kg < 256) ? (head + kg) : (tail + (kg - 256));
            aNxt.v[0] = *(const float4*)(srcb + arow * 256 + akc);
            aNxt.v[1] = *(const float4*)(srcb + arow * 256 + akc + 4);
#pragma unroll
            for (int nt = 0; nt < 4; ++nt)
                wNxt[nt].v = *(const int4*)(WT + (long)(n0 + nt * 16 + l15) * 512 + kg + quad * 8);
        } else {
            aNxt = aCur;
#pragma unroll
            for (int nt = 0; nt < 4; ++nt) wNxt[nt] = wCur[nt];
        }

        V16h af[4];
#pragma unroll
        for (int mb = 0; mb < 4; ++mb)
            af[mb].v = *(const int4*)&sA[ks & 1][(mb * 16 + l15) * 32 + quad * 8];
#pragma unroll
        for (int mb = 0; mb < 4; ++mb)
#pragma unroll
            for (int nt = 0; nt < 4; ++nt)
                acc[mb][nt] = __builtin_amdgcn_mfma_f32_16x16x32_f16(af[mb].h8, wCur[nt].h8, acc[mb][nt], 0, 0, 0);

        aCur = aNxt;
#pragma unroll
        for (int nt = 0; nt < 4; ++nt) wCur[nt] = wNxt[nt];
    }

    float bias[4];
#pragma unroll
    for (int nt = 0; nt < 4; ++nt) bias[nt] = brel[n0 + nt * 16 + l15];

#pragma unroll
    for (int mb = 0; mb < 4; ++mb)
#pragma unroll
        for (int nt = 0; nt < 4; ++nt) {
            H4 hq;
#pragma unroll
            for (int r = 0; r < 4; ++r) {
                const long row = m0 + mb * 16 + quad * 4 + r;
                const _Float16 h = (_Float16)(acc[mb][nt][r] + bias[nt]);
                Ef[row * 256 + n0 + nt * 16 + l15] = h;
                hq.h[r] = h;
            }
            if (!isQ) {
                const int n  = n0 + nt * 16 + l15;
                const int sw = (mb * 4 + quad) ^ l15;
                *(uint2*)&sO[n * 64 + sw * 4] = hq.u;
            }
        }

    if (!isQ) {
        __syncthreads();
        const int bidx = (int)(m0 >> 12);
        const int jc0  = (int)(m0 & 4095);
        const int c    = tid & 7;
        const int nl   = tid >> 3;
#pragma unroll
        for (int i = 0; i < 8; ++i) {
            const int n  = nl + 32 * i;
            const int s0 = (2 * c)     ^ (n & 15);
            const int s1 = (2 * c + 1) ^ (n & 15);
            const uint2 u0 = *(const uint2*)&sO[n * 64 + s0 * 4];
            const uint2 u1 = *(const uint2*)&sO[n * 64 + s1 * 4];
            int4 out; out.x = u0.x; out.y = u0.y; out.z = u1.x; out.w = u1.y;
            *(int4*)&CfT[(long)bidx * 1048576 + (long)n * 4096 + jc0 + c * 8] = out;
        }
    }
}

// ---------------------------------------------------------------------------
// gen head: genlog[8192][32] = q_emb @ [Wgen | Wcp_q] (+bgen).
// ---------------------------------------------------------------------------
__global__ __launch_bounds__(256, 4) void gen_kernel(
    const _Float16* __restrict__ Qf,
    const _Float16* __restrict__ GenB,
    const float* __restrict__ bgen,
    float* __restrict__ genlog)
{
    const int tid  = threadIdx.x;
    const int lane = tid & 63;
    const int wv   = tid >> 6;
    const int l15  = lane & 15;
    const int quad = lane >> 4;
    const long m0  = (long)blockIdx.x * 64 + wv * 16;

    floatx4 acc[2];
    acc[0] = (floatx4)(0.0f); acc[1] = (floatx4)(0.0f);
#pragma unroll
    for (int ks = 0; ks < 8; ++ks) {
        V16h a, b0, b1;
        a.v  = *(const int4*)(Qf + (m0 + l15) * 256 + ks * 32 + quad * 8);
        b0.v = *(const int4*)(GenB + (long)(l15)      * 256 + ks * 32 + quad * 8);
        b1.v = *(const int4*)(GenB + (long)(16 + l15) * 256 + ks * 32 + quad * 8);
        acc[0] = __builtin_amdgcn_mfma_f32_16x16x32_f16(a.h8, b0.h8, acc[0], 0, 0, 0);
        acc[1] = __builtin_amdgcn_mfma_f32_16x16x32_f16(a.h8, b1.h8, acc[1], 0, 0, 0);
    }
#pragma unroll
    for (int nt = 0; nt < 2; ++nt) {
        const int col = nt * 16 + l15;
        const float bias = (col < 25) ? bgen[col] : 0.f;
#pragma unroll
        for (int r = 0; r < 4; ++r)
            genlog[(m0 + quad * 4 + r) * 32 + col] = acc[nt][r] + bias;
    }
}

// ---------------------------------------------------------------------------
// Fused flash attention + grouped class sums. 256 thr, q-tile 64, j-tile 32.
// grid 16qt*8b*ns, XCD swizzle. R6 proven structure: dbuf sA+sB staged
// together, ONE barrier/iter, bounds(256,2). Added: mask/label prefetch
// (1 iter ahead, in regs) + wave-uniform alpha-skip.
// ---------------------------------------------------------------------------
__global__ __launch_bounds__(256, 2) void attn_kernel(
    const _Float16* __restrict__ qf,
    const _Float16* __restrict__ cf,
    const _Float16* __restrict__ cfT,
    const int*      __restrict__ labels,
    const float*    __restrict__ maskp,
    unsigned short* __restrict__ Oh,    // fp16 [ns*8192][288]
    float* __restrict__ Mst,
    float* __restrict__ Lst,
    int jtiles, int nsh)
{
    __shared__ _Float16 sA[2][8192];    // 2 x 16 KB natural c tile
    __shared__ _Float16 sB[2][8192];    // 2 x 16 KB transposed c tile
    __shared__ _Float16 Pw[4][16 * 40]; // 5 KB per-wave P

    const int tid  = threadIdx.x;
    const int lane = tid & 63;
    const int wv   = tid >> 6;
    const int l15  = lane & 15;
    const int quad = lane >> 4;

    const int f   = blockIdx.x;
    const int xcd = f & 7;
    const int seq = f >> 3;
    const int qt  = seq & 15;
    const int u   = seq >> 4;
    const int pr  = u * 8 + xcd;
    const int b   = pr >> nsh;
    const int sp  = pr & ((1 << nsh) - 1);
    const int q0  = qt * 64;

    V16h qfr[8];
    {
        const long qrow = (long)b * WNQ + q0 + wv * 16 + l15;
#pragma unroll
        for (int ks = 0; ks < 8; ++ks)
            qfr[ks].v = *(const int4*)(qf + qrow * 256 + ks * 32 + quad * 8);
    }

    floatx4 O[18];
#pragma unroll
    for (int i = 0; i < 18; ++i) O[i] = (floatx4)(0.0f);
    float m_run = -INFINITY, l_run = 0.f;

    const int jb0 = sp * (jtiles * 32);

    auto stage = [&](int bf, int jb) {
        const long cbase = ((long)b * WNC + jb) * 256;
#pragma unroll
        for (int t = 0; t < 4; ++t) {
            const int idx = wv * 4 + t;            // 0..15
            const int ks = idx >> 1, jh = idx & 1;
            async_lds16(cf + cbase + (jh * 16 + l15) * 256 + ks * 32 + quad * 8,
                        &sA[bf][idx * 512]);
        }
        const long tbase = (long)b * 1048576 + jb;
#pragma unroll
        for (int t = 0; t < 4; ++t) {
            const int W = wv * 4 + t;              // d-block 0..15
            async_lds16(cfT + tbase + (long)(W * 16 + (lane >> 2)) * 4096 + (lane & 3) * 8,
                        &sB[bf][W * 512]);
        }
    };

    stage(0, jb0);
    // prefetch mask + labels for it=0
    float4 mv0c = *(const float4*)(maskp + (long)b * WNC + jb0 + quad * 4);
    float4 mv1c = *(const float4*)(maskp + (long)b * WNC + jb0 + 16 + quad * 4);
    int4   lb0c = *(const int4*)(labels + (long)b * WNC + jb0 + quad * 8);
    int4   lb1c = *(const int4*)(labels + (long)b * WNC + jb0 + quad * 8 + 4);

    for (int it = 0; it < jtiles; ++it) {
        const int cur = it & 1;
        const int jb  = jb0 + it * 32;
        __syncthreads();                       // buf[cur] ready
        if (it + 1 < jtiles) stage(cur ^ 1, jb + 32);

        // prefetch next iter's mask/labels (used NEXT iter; latency hidden)
        const int jbn = (it + 1 < jtiles) ? jb + 32 : jb;
        const float4 mv0n = *(const float4*)(maskp + (long)b * WNC + jbn + quad * 4);
        const float4 mv1n = *(const float4*)(maskp + (long)b * WNC + jbn + 16 + quad * 4);
        const int4   lb0n = *(const int4*)(labels + (long)b * WNC + jbn + quad * 8);
        const int4   lb1n = *(const int4*)(labels + (long)b * WNC + jbn + quad * 8 + 4);

        // ---- S^T = c (A from sA) . q^T (B regs) ----
        floatx4 accS0 = (floatx4)(0.0f), accS1 = (floatx4)(0.0f);
#pragma unroll
        for (int ks = 0; ks < 8; ++ks) {
            V16h a0, a1;
            a0.v = *(const int4*)&sA[cur][(ks * 2 + 0) * 512 + (quad * 16 + l15) * 8];
            a1.v = *(const int4*)&sA[cur][(ks * 2 + 1) * 512 + (quad * 16 + l15) * 8];
            accS0 = __builtin_amdgcn_mfma_f32_16x16x32_f16(a0.h8, qfr[ks].h8, accS0, 0, 0, 0);
            accS1 = __builtin_amdgcn_mfma_f32_16x16x32_f16(a1.h8, qfr[ks].h8, accS1, 0, 0, 0);
        }
        const float* mv0p = (const float*)&mv0c;
        const float* mv1p = (const float*)&mv1c;
#pragma unroll
        for (int r = 0; r < 4; ++r) {
            accS0[r] *= mv0p[r];
            accS1[r] *= mv1p[r];
        }

        // ---- online softmax per q = lane&15 ----
        float v = fmaxf(fmaxf(fmaxf(accS0[0], accS0[1]), fmaxf(accS0[2], accS0[3])),
                        fmaxf(fmaxf(accS1[0], accS1[1]), fmaxf(accS1[2], accS1[3])));
        v = fmaxf(v, __shfl_xor(v, 16, 64));
        v = fmaxf(v, __shfl_xor(v, 32, 64));
        const float m_new = fmaxf(m_run, v);
        const bool upd = __any(m_new > m_run);
        const float alpha = __expf(m_run - m_new);
        float p[8]; float ts = 0.f;
#pragma unroll
        for (int r = 0; r < 4; ++r) {
            p[r]     = __expf(accS0[r] - m_new); ts += p[r];
            p[4 + r] = __expf(accS1[r] - m_new); ts += p[4 + r];
        }
        ts += __shfl_xor(ts, 16, 64);
        ts += __shfl_xor(ts, 32, 64);
        l_run = l_run * alpha + ts;
        m_run = m_new;

        if (upd) {
            float ar[4];
#pragma unroll
            for (int r = 0; r < 4; ++r) ar[r] = __shfl(alpha, quad * 4 + r, 64);
#pragma unroll
            for (int fo = 0; fo < 18; ++fo)
#pragma unroll
                for (int r = 0; r < 4; ++r) O[fo][r] *= ar[r];
        }

        // ---- P -> per-wave LDS (A layout [q][j]) ----
#pragma unroll
        for (int jf = 0; jf < 2; ++jf) {
            H4 w;
#pragma unroll
            for (int r = 0; r < 4; ++r) w.h[r] = (_Float16)p[jf * 4 + r];
            *(uint2*)&Pw[wv][l15 * 40 + jf * 16 + quad * 4] = w.u;
        }
        asm volatile("" ::: "memory");
        V16h pf;
        pf.v = *(const int4*)&Pw[wv][l15 * 40 + quad * 8];

        const int* lbp0 = (const int*)&lb0c;
        const int* lbp1 = (const int*)&lb1c;
        V16h oh0, oh1;
#pragma unroll
        for (int i = 0; i < 8; ++i) {
            const int lv = (i < 4) ? lbp0[i] : lbp1[i - 4];
            oh0.h[i] = (lv == l15)        ? (_Float16)1.0f : (_Float16)0.0f;
            oh1.h[i] = (lv == (l15 + 16)) ? (_Float16)1.0f : (_Float16)0.0f;
        }

        // ---- O += P @ [c | onehot] (B from sB) ----
#pragma unroll
        for (int dt = 0; dt < 16; ++dt) {
            V16h bfr;
            bfr.v = *(const int4*)&sB[cur][((dt * 16 + l15) * 4 + quad) * 8];
            O[dt] = __builtin_amdgcn_mfma_f32_16x16x32_f16(pf.h8, bfr.h8, O[dt], 0, 0, 0);
        }
        O[16] = __builtin_amdgcn_mfma_f32_16x16x32_f16(pf.h8, oh0.h8, O[16], 0, 0, 0);
        O[17] = __builtin_amdgcn_mfma_f32_16x16x32_f16(pf.h8, oh1.h8, O[17], 0, 0, 0);

        mv0c = mv0n; mv1c = mv1n; lb0c = lb0n; lb1c = lb1n;
    }

    {
        const long base = (long)(sp * WB + b) * WNQ + q0 + wv * 16;
#pragma unroll
        for (int dt = 0; dt < 18; ++dt)
#pragma unroll
            for (int r = 0; r < 4; ++r) {
                H4 h; h.h[0] = (_Float16)O[dt][r];
                Oh[(base + quad * 4 + r) * 288 + dt * 16 + l15] = h.s[0];
            }
        if (lane < 16) {
            Mst[base + lane] = m_run;
            Lst[base + lane] = l_run;
        }
    }
}

// ---------------------------------------------------------------------------
// Combine splits + log_softmax(gen) + gate + logaddexp. 4 rows per block.
// ---------------------------------------------------------------------------
__global__ __launch_bounds__(256) void final_kernel(
    const float* __restrict__ genlog,
    const unsigned short* __restrict__ Oh,
    const float* __restrict__ Mst,
    const float* __restrict__ Lst,
    const float* __restrict__ Wcp,
    const float* __restrict__ bcp,
    float* __restrict__ outp,
    int ns)
{
    __shared__ float gA[4][32];
    __shared__ float cdA[4][32];

    const int tid  = threadIdx.x;
    const int lane = tid & 63;
    const int wv   = tid >> 6;
    const int row  = blockIdx.x * 4 + wv;

    float ms[8];
#pragma unroll
    for (int s = 0; s < 8; ++s) ms[s] = (s < ns) ? Mst[(long)s * NROWS + row] : -INFINITY;
    float mstar = -INFINITY;
#pragma unroll
    for (int s = 0; s < 8; ++s) mstar = fmaxf(mstar, ms[s]);
    float wgt[8]; float L = 0.f;
#pragma unroll
    for (int s = 0; s < 8; ++s) {
        wgt[s] = (ms[s] == -INFINITY) ? 0.f : __expf(ms[s] - mstar);
        if (s < ns) L += Lst[(long)s * NROWS + row] * wgt[s];
    }

    const int d0 = lane * 4;
    float ctx[4] = {0.f, 0.f, 0.f, 0.f};
#pragma unroll
    for (int s = 0; s < 8; ++s) {
        if (s < ns) {
            H4 t; t.u = *(const uint2*)&Oh[((long)s * NROWS + row) * 288 + d0];
#pragma unroll
            for (int i = 0; i < 4; ++i) ctx[i] += wgt[s] * (float)t.h[i];
        }
    }

    float cls[4] = {0.f, 0.f, 0.f, 0.f};
    if (lane < 8) {
#pragma unroll
        for (int s = 0; s < 8; ++s) {
            if (s < ns) {
                H4 t; t.u = *(const uint2*)&Oh[((long)s * NROWS + row) * 288 + 256 + lane * 4];
#pragma unroll
                for (int i = 0; i < 4; ++i) cls[i] += wgt[s] * (float)t.h[i];
            }
        }
    }

    float g = (lane < 25) ? genlog[(long)row * 32 + lane] : -INFINITY;
    float mg = g;
#pragma unroll
    for (int off = 32; off >= 1; off >>= 1) mg = fmaxf(mg, __shfl_xor(mg, off, 64));
    float se = (lane < 25) ? __expf(g - mg) : 0.f;
#pragma unroll
    for (int off = 32; off >= 1; off >>= 1) se += __shfl_xor(se, off, 64);
    const float glsm = g - mg - logf(se);

    const float qgate = genlog[(long)row * 32 + 25];
    const float invL = 1.f / L;
    float part = 0.f;
#pragma unroll
    for (int i = 0; i < 4; ++i)
        part += ctx[i] * invL * Wcp[256 + d0 + i];
#pragma unroll
    for (int off = 32; off >= 1; off >>= 1) part += __shfl_xor(part, off, 64);
    const float logit = qgate + part + bcp[0];

    const float lscp  = logsig(logit);
    const float lsgen = logsig(-logit);
    const float logL  = logf(L);

    if (lane < 8) {
#pragma unroll
        for (int i = 0; i < 4; ++i)
            cdA[wv][lane * 4 + i] = (cls[i] > 0.f) ? (logf(cls[i]) - logL) : -INFINITY;
    }
    if (lane < 25) gA[wv][lane] = glsm;
    __syncthreads();

    if (lane < 25) {
        const float a  = lscp + cdA[wv][lane];
        const float bb = lsgen + gA[wv][lane];
        const float mx = fmaxf(a, bb);
        const float o  = (mx == -INFINITY) ? -INFINITY
                         : mx + log1pf(__expf(fminf(a, bb) - mx));
        outp[(long)row * 25 + lane] = o;
    }
}

// ---------------------------------------------------------------------------
extern "C" void kernel_launch(void* const* d_in, const int* in_sizes, int n_in,
                              void* d_out, int out_size, void* d_ws, size_t ws_size,
                              hipStream_t stream) {
    const float* q_head = (const float*)d_in[0];
    const float* q_tail = (const float*)d_in[1];
    const float* c_head = (const float*)d_in[2];
    const float* c_tail = (const float*)d_in[3];
    const int*   labels = (const int*)d_in[4];
    const float* maskp  = (const float*)d_in[5];
    const float* Wrel   = (const float*)d_in[6];
    const float* brel   = (const float*)d_in[7];
    const float* Wgen   = (const float*)d_in[8];
    const float* bgen   = (const float*)d_in[9];
    const float* Wcp    = (const float*)d_in[10];
    const float* bcp    = (const float*)d_in[11];

    auto need = [](long ns) -> long { return 39075840l + ns * 4784128l; };
    int ns = 8, nsh = 3;
    if ((long)ws_size < need(8)) { ns = 4; nsh = 2; }
    if ((long)ws_size < need(4)) { ns = 2; nsh = 1; }
    if ((long)ws_size < need(2)) { ns = 1; nsh = 0; }
    const int jtiles = 128 / ns;

    char* ws = (char*)d_ws;
    _Float16* Qf     = (_Float16*)(ws);                   //  4 MB
    _Float16* Cf     = (_Float16*)(ws + 4194304l);        // 16 MB
    _Float16* CfT    = (_Float16*)(ws + 20971520l);       // 16 MB
    _Float16* WT     = (_Float16*)(ws + 37748736l);       // 256 KB
    _Float16* GenB   = (_Float16*)(ws + 38010880l);       // 16 KB
    float*    genlog = (float*)   (ws + 38027264l);       //  1 MB
    unsigned short* Oh = (unsigned short*)(ws + 39075840l);  // ns*4.5 MB fp16
    float*    Mst    = (float*)   (ws + 39075840l + (long)ns * 4718592l);
    float*    Lst    = Mst + (long)ns * NROWS;

    hipLaunchKernelGGL(wprep_kernel, dim3(288), dim3(256), 0, stream,
                       Wrel, Wgen, Wcp, WT, GenB);
    hipLaunchKernelGGL(emb_kernel, dim3(640), dim3(256), 0, stream,
                       q_head, q_tail, c_head, c_tail, WT, brel, Qf, Cf, CfT);
    hipLaunchKernelGGL(gen_kernel, dim3(128), dim3(256), 0, stream,
                       Qf, GenB, bgen, genlog);
    hipLaunchKernelGGL(attn_kernel, dim3(16 * 8 * ns), dim3(256), 0, stream,
                       Qf, Cf, CfT, labels, maskp, Oh, Mst, Lst, jtiles, nsh);
    hipLaunchKernelGGL(final_kernel, dim3(NROWS / 4), dim3(256), 0, stream,
                       genlog, Oh, Mst, Lst, Wcp, bcp, (float*)d_out, ns);
}

// Round 10
// 265.306 us; speedup vs baseline: 1.7421x; 1.0072x over previous
//
#include <hip/hip_runtime.h>

// B=8, NQ=1024, NC=4096, D=256, C+1=25. FP32 I/O; labels int32.
// R10: attn 37KB LDS (sA/sB single-buffered, 2 barriers/iter) -> 4 blk/CU,
// cross-block overlap hides staging; l via ones-column MFMA (no sum shuffles);
// gen head fused into emb q-blocks. Register-light (no cross-iter prefetch).

typedef __attribute__((ext_vector_type(8))) _Float16 half8;
typedef __attribute__((ext_vector_type(4))) float floatx4;

#define WB 8
#define WNQ 1024
#define WNC 4096
#define NROWS 8192          // B*NQ

static __device__ __forceinline__ float logsig(float x) {
    return (x >= 0.f) ? -log1pf(__expf(-x)) : x - log1pf(__expf(x));
}

union V16h { int4 v; half8 h8; _Float16 h[8]; unsigned short s[8]; uint2 u2[2]; };
union F8   { float4 v[2]; float f[8]; };
union H4   { _Float16 h[4]; uint2 u; unsigned short s[4]; };

static __device__ __forceinline__ void async_lds16(const _Float16* g, _Float16* l) {
    __builtin_amdgcn_global_load_lds(
        (const __attribute__((address_space(1))) unsigned int*)g,
        (__attribute__((address_space(3))) unsigned int*)l,
        16, 0, 0);
}

// ---------------------------------------------------------------------------
// wprep: WT fp16 [256 n][512 k] = W_rel^T; GenB fp16 [32 n][256 k].
// ---------------------------------------------------------------------------
__global__ void wprep_kernel(const float* __restrict__ Wrel,
                             const float* __restrict__ Wgen,
                             const float* __restrict__ Wcp,
                             _Float16* __restrict__ WT,
                             _Float16* __restrict__ GenB)
{
    const int bx = blockIdx.x;
    if (bx < 256) {
        const int n = bx;
        for (int k = threadIdx.x; k < 512; k += 256)
            WT[(long)n * 512 + k] = (_Float16)Wrel[(long)k * 256 + n];
    } else {
        const int n = bx - 256;
        const int k = threadIdx.x;
        float v = 0.f;
        if (n < 25)       v = Wgen[(long)k * 25 + n];
        else if (n == 25) v = Wcp[k];
        GenB[(long)n * 256 + k] = (_Float16)v;
    }
}

// ---------------------------------------------------------------------------
// emb: concat(head,tail) @ W_rel + b_rel -> fp16. Blocks 0..127 q (+fused
// gen head via natural LDS tile), 128..639 c (+transposed CfT via swizzled
// LDS bounce). 64m x 256n per block, 4 waves, dbuf'd pipelined K-loop.
// ---------------------------------------------------------------------------
__global__ __launch_bounds__(256, 2) void emb_kernel(
    const float* __restrict__ q_head, const float* __restrict__ q_tail,
    const float* __restrict__ c_head, const float* __restrict__ c_tail,
    const _Float16* __restrict__ WT,
    const float* __restrict__ brel,
    const _Float16* __restrict__ GenB,
    const float* __restrict__ bgen,
    _Float16* __restrict__ Qf, _Float16* __restrict__ Cf,
    _Float16* __restrict__ CfT,
    float* __restrict__ genlog)
{
    __shared__ _Float16 sA[2][2048];   // 8 KB dbuf A-tile fp16
    __shared__ _Float16 sO[64 * 264];  // 33 KB: q natural [m][264] / c swizzled

    const int tid  = threadIdx.x;
    const int lane = tid & 63;
    const int wv   = tid >> 6;
    const int l15  = lane & 15;
    const int quad = lane >> 4;
    const int n0   = wv * 64;

    const float* head; const float* tail; _Float16* Ef;
    long m0; bool isQ;
    if (blockIdx.x < 128) {
        isQ = true;  head = q_head; tail = q_tail; Ef = Qf;
        m0 = (long)blockIdx.x * 64;
    } else {
        isQ = false; head = c_head; tail = c_tail; Ef = Cf;
        m0 = (long)(blockIdx.x - 128) * 64;
    }

    const long arow = m0 + (tid >> 2);
    const int  akc  = (tid & 3) * 8;

    floatx4 acc[4][4];
#pragma unroll
    for (int a = 0; a < 4; ++a)
#pragma unroll
        for (int bq = 0; bq < 4; ++bq) acc[a][bq] = (floatx4)(0.0f);

    F8 aCur;
    aCur.v[0] = *(const float4*)(head + arow * 256 + akc);
    aCur.v[1] = *(const float4*)(head + arow * 256 + akc + 4);
    V16h wCur[4];
#pragma unroll
    for (int nt = 0; nt < 4; ++nt)
        wCur[nt].v = *(const int4*)(WT + (long)(n0 + nt * 16 + l15) * 512 + quad * 8);

    for (int ks = 0; ks < 16; ++ks) {
        {
            V16h hp;
#pragma unroll
            for (int i = 0; i < 8; ++i) hp.h[i] = (_Float16)aCur.f[i];
            *(int4*)&sA[ks & 1][tid * 8] = hp.v;
        }
        __syncthreads();                 // drains LDS write AND last iter's loads

        F8 aNxt; V16h wNxt[4];
        if (ks < 15) {                   // issued AFTER barrier -> drain next iter
            const int kg = (ks + 1) * 32;
            const float* srcb = (kg < 256) ? (head + kg) : (tail + (kg - 256));
            aNxt.v[0] = *(const float4*)(srcb + arow * 256 + akc);
            aNxt.v[1] = *(const float4*)(srcb + arow * 256 + akc + 4);
#pragma unroll
            for (int nt = 0; nt < 4; ++nt)
                wNxt[nt].v = *(const int4*)(WT + (long)(n0 + nt * 16 + l15) * 512 + kg + quad * 8);
        } else {
            aNxt = aCur;
#pragma unroll
            for (int nt = 0; nt < 4; ++nt) wNxt[nt] = wCur[nt];
        }

        V16h af[4];
#pragma unroll
        for (int mb = 0; mb < 4; ++mb)
            af[mb].v = *(const int4*)&sA[ks & 1][(mb * 16 + l15) * 32 + quad * 8];
#pragma unroll
        for (int mb = 0; mb < 4; ++mb)
#pragma unroll
            for (int nt = 0; nt < 4; ++nt)
                acc[mb][nt] = __builtin_amdgcn_mfma_f32_16x16x32_f16(af[mb].h8, wCur[nt].h8, acc[mb][nt], 0, 0, 0);

        aCur = aNxt;
#pragma unroll
        for (int nt = 0; nt < 4; ++nt) wCur[nt] = wNxt[nt];
    }

    float bias[4];
#pragma unroll
    for (int nt = 0; nt < 4; ++nt) bias[nt] = brel[n0 + nt * 16 + l15];

#pragma unroll
    for (int mb = 0; mb < 4; ++mb)
#pragma unroll
        for (int nt = 0; nt < 4; ++nt) {
            H4 hq;
#pragma unroll
            for (int r = 0; r < 4; ++r) {
                const long row = m0 + mb * 16 + quad * 4 + r;
                const _Float16 h = (_Float16)(acc[mb][nt][r] + bias[nt]);
                Ef[row * 256 + n0 + nt * 16 + l15] = h;
                hq.h[r] = h;
                if (isQ)   // natural tile for fused gen head
                    sO[(mb * 16 + quad * 4 + r) * 264 + n0 + nt * 16 + l15] = h;
            }
            if (!isQ) {
                const int n  = n0 + nt * 16 + l15;
                const int sw = (mb * 4 + quad) ^ l15;
                *(uint2*)&sO[n * 64 + sw * 4] = hq.u;
            }
        }

    __syncthreads();
    if (isQ) {
        // ---- fused gen head: genlog[m][32] = q_emb @ GenB^T (+bgen) ----
        floatx4 ga[2];
        ga[0] = (floatx4)(0.0f); ga[1] = (floatx4)(0.0f);
#pragma unroll
        for (int ks = 0; ks < 8; ++ks) {
            V16h a, b0, b1;
            a.v  = *(const int4*)&sO[(wv * 16 + l15) * 264 + ks * 32 + quad * 8];
            b0.v = *(const int4*)(GenB + (long)(l15)      * 256 + ks * 32 + quad * 8);
            b1.v = *(const int4*)(GenB + (long)(16 + l15) * 256 + ks * 32 + quad * 8);
            ga[0] = __builtin_amdgcn_mfma_f32_16x16x32_f16(a.h8, b0.h8, ga[0], 0, 0, 0);
            ga[1] = __builtin_amdgcn_mfma_f32_16x16x32_f16(a.h8, b1.h8, ga[1], 0, 0, 0);
        }
#pragma unroll
        for (int nt = 0; nt < 2; ++nt) {
            const int col = nt * 16 + l15;
            const float bb = (col < 25) ? bgen[col] : 0.f;
#pragma unroll
            for (int r = 0; r < 4; ++r)
                genlog[(m0 + wv * 16 + quad * 4 + r) * 32 + col] = ga[nt][r] + bb;
        }
    } else {
        const int bidx = (int)(m0 >> 12);
        const int jc0  = (int)(m0 & 4095);
        const int c    = tid & 7;
        const int nl   = tid >> 3;
#pragma unroll
        for (int i = 0; i < 8; ++i) {
            const int n  = nl + 32 * i;
            const int s0 = (2 * c)     ^ (n & 15);
            const int s1 = (2 * c + 1) ^ (n & 15);
            const uint2 u0 = *(const uint2*)&sO[n * 64 + s0 * 4];
            const uint2 u1 = *(const uint2*)&sO[n * 64 + s1 * 4];
            int4 out; out.x = u0.x; out.y = u0.y; out.z = u1.x; out.w = u1.y;
            *(int4*)&CfT[(long)bidx * 1048576 + (long)n * 4096 + jc0 + c * 8] = out;
        }
    }
}

// ---------------------------------------------------------------------------
// Fused flash attention + grouped class sums. 256 thr, q-tile 64, j-tile 32.
// grid 16qt*8b*ns, XCD swizzle. 37.25 KB LDS (sA/sB SINGLE-buffered) ->
// 4 blocks/CU; per iter: barrier(readers done) -> stage async + mask/labels
// -> barrier(vmcnt drain) -> compute. Cross-block overlap hides the drain.
// l via ones-column MFMA (B col 31 == 1 -> O[17] accumulates row sums).
// ---------------------------------------------------------------------------
__global__ __launch_bounds__(256, 2) void attn_kernel(
    const _Float16* __restrict__ qf,
    const _Float16* __restrict__ cf,
    const _Float16* __restrict__ cfT,
    const int*      __restrict__ labels,
    const float*    __restrict__ maskp,
    unsigned short* __restrict__ Oh,    // fp16 [ns*8192][288]
    float* __restrict__ Mst,
    float* __restrict__ Lst,
    int jtiles, int nsh)
{
    __shared__ _Float16 sA[8192];       // 16 KB natural c tile
    __shared__ _Float16 sB[8192];       // 16 KB transposed c tile
    __shared__ _Float16 Pw[4][16 * 40]; //  5 KB per-wave P

    const int tid  = threadIdx.x;
    const int lane = tid & 63;
    const int wv   = tid >> 6;
    const int l15  = lane & 15;
    const int quad = lane >> 4;

    const int f   = blockIdx.x;
    const int xcd = f & 7;
    const int seq = f >> 3;
    const int qt  = seq & 15;
    const int u   = seq >> 4;
    const int pr  = u * 8 + xcd;
    const int b   = pr >> nsh;
    const int sp  = pr & ((1 << nsh) - 1);
    const int q0  = qt * 64;

    V16h qfr[8];
    {
        const long qrow = (long)b * WNQ + q0 + wv * 16 + l15;
#pragma unroll
        for (int ks = 0; ks < 8; ++ks)
            qfr[ks].v = *(const int4*)(qf + qrow * 256 + ks * 32 + quad * 8);
    }

    floatx4 O[18];
#pragma unroll
    for (int i = 0; i < 18; ++i) O[i] = (floatx4)(0.0f);
    float m_run = -INFINITY;

    const int jb0 = sp * (jtiles * 32);

    for (int it = 0; it < jtiles; ++it) {
        const int jb = jb0 + it * 32;
        __syncthreads();                       // all waves done reading prev tile
        {   // ---- async stage current tile ----
            const long cbase = ((long)b * WNC + jb) * 256;
#pragma unroll
            for (int t = 0; t < 4; ++t) {
                const int idx = wv * 4 + t;            // 0..15
                const int ks = idx >> 1, jh = idx & 1;
                async_lds16(cf + cbase + (jh * 16 + l15) * 256 + ks * 32 + quad * 8,
                            &sA[idx * 512]);
            }
            const long tbase = (long)b * 1048576 + jb;
#pragma unroll
            for (int t = 0; t < 4; ++t) {
                const int W = wv * 4 + t;              // d-block 0..15
                async_lds16(cfT + tbase + (long)(W * 16 + (lane >> 2)) * 4096 + (lane & 3) * 8,
                            &sB[W * 512]);
            }
        }
        // mask + labels (land during the drain below)
        const float4 mv0 = *(const float4*)(maskp + (long)b * WNC + jb + quad * 4);
        const float4 mv1 = *(const float4*)(maskp + (long)b * WNC + jb + 16 + quad * 4);
        const int4   lb0 = *(const int4*)(labels + (long)b * WNC + jb + quad * 8);
        const int4   lb1 = *(const int4*)(labels + (long)b * WNC + jb + quad * 8 + 4);
        __syncthreads();                       // vmcnt(0) drained -> tile ready

        // ---- S^T = c (A from sA) . q^T (B regs) ----
        floatx4 accS0 = (floatx4)(0.0f), accS1 = (floatx4)(0.0f);
#pragma unroll
        for (int ks = 0; ks < 8; ++ks) {
            V16h a0, a1;
            a0.v = *(const int4*)&sA[(ks * 2 + 0) * 512 + (quad * 16 + l15) * 8];
            a1.v = *(const int4*)&sA[(ks * 2 + 1) * 512 + (quad * 16 + l15) * 8];
            accS0 = __builtin_amdgcn_mfma_f32_16x16x32_f16(a0.h8, qfr[ks].h8, accS0, 0, 0, 0);
            accS1 = __builtin_amdgcn_mfma_f32_16x16x32_f16(a1.h8, qfr[ks].h8, accS1, 0, 0, 0);
        }
        const float* mv0p = (const float*)&mv0;
        const float* mv1p = (const float*)&mv1;
#pragma unroll
        for (int r = 0; r < 4; ++r) {
            accS0[r] *= mv0p[r];
            accS1[r] *= mv1p[r];
        }

        // ---- online max per q = lane&15 ----
        float v = fmaxf(fmaxf(fmaxf(accS0[0], accS0[1]), fmaxf(accS0[2], accS0[3])),
                        fmaxf(fmaxf(accS1[0], accS1[1]), fmaxf(accS1[2], accS1[3])));
        v = fmaxf(v, __shfl_xor(v, 16, 64));
        v = fmaxf(v, __shfl_xor(v, 32, 64));
        const float m_new = fmaxf(m_run, v);
        const bool upd = __any(m_new > m_run);
        const float alpha = __expf(m_run - m_new);
        float p[8];
#pragma unroll
        for (int r = 0; r < 4; ++r) {
            p[r]     = __expf(accS0[r] - m_new);
            p[4 + r] = __expf(accS1[r] - m_new);
        }
        m_run = m_new;

        if (upd) {
            float ar[4];
#pragma unroll
            for (int r = 0; r < 4; ++r) ar[r] = __shfl(alpha, quad * 4 + r, 64);
#pragma unroll
            for (int fo = 0; fo < 18; ++fo)
#pragma unroll
                for (int r = 0; r < 4; ++r) O[fo][r] *= ar[r];
        }

        // ---- P -> per-wave LDS (A layout [q][j]) ----
#pragma unroll
        for (int jf = 0; jf < 2; ++jf) {
            H4 w;
#pragma unroll
            for (int r = 0; r < 4; ++r) w.h[r] = (_Float16)p[jf * 4 + r];
            *(uint2*)&Pw[wv][l15 * 40 + jf * 16 + quad * 4] = w.u;
        }
        asm volatile("" ::: "memory");
        V16h pf;
        pf.v = *(const int4*)&Pw[wv][l15 * 40 + quad * 8];

        const int* lbp0 = (const int*)&lb0;
        const int* lbp1 = (const int*)&lb1;
        V16h oh0, oh1;
#pragma unroll
        for (int i = 0; i < 8; ++i) {
            const int lv = (i < 4) ? lbp0[i] : lbp1[i - 4];
            oh0.h[i] = (lv == l15)        ? (_Float16)1.0f : (_Float16)0.0f;
            // col 31 (l15==15): all-ones column accumulates l in O[17]
            oh1.h[i] = (lv == (l15 + 16) || l15 == 15) ? (_Float16)1.0f : (_Float16)0.0f;
        }

        // ---- O += P @ [c | onehot+ones] (B from sB) ----
#pragma unroll
        for (int dt = 0; dt < 16; ++dt) {
            V16h bfr;
            bfr.v = *(const int4*)&sB[((dt * 16 + l15) * 4 + quad) * 8];
            O[dt] = __builtin_amdgcn_mfma_f32_16x16x32_f16(pf.h8, bfr.h8, O[dt], 0, 0, 0);
        }
        O[16] = __builtin_amdgcn_mfma_f32_16x16x32_f16(pf.h8, oh0.h8, O[16], 0, 0, 0);
        O[17] = __builtin_amdgcn_mfma_f32_16x16x32_f16(pf.h8, oh1.h8, O[17], 0, 0, 0);
    }

    {
        const long base = (long)(sp * WB + b) * WNQ + q0 + wv * 16;
#pragma unroll
        for (int dt = 0; dt < 18; ++dt)
#pragma unroll
            for (int r = 0; r < 4; ++r) {
                H4 h; h.h[0] = (_Float16)O[dt][r];
                Oh[(base + quad * 4 + r) * 288 + dt * 16 + l15] = h.s[0];
            }
        if (lane < 16) Mst[base + lane] = m_run;
        if (l15 == 15) {
#pragma unroll
            for (int r = 0; r < 4; ++r)
                Lst[base + quad * 4 + r] = O[17][r];   // ones-column = l
        }
    }
}

// ---------------------------------------------------------------------------
// Combine splits + log_softmax(gen) + gate + logaddexp. 4 rows per block.
// ---------------------------------------------------------------------------
__global__ __launch_bounds__(256) void final_kernel(
    const float* __restrict__ genlog,
    const unsigned short* __restrict__ Oh,
    const float* __restrict__ Mst,
    const float* __restrict__ Lst,
    const float* __restrict__ Wcp,
    const float* __restrict__ bcp,
    float* __restrict__ outp,
    int ns)
{
    __shared__ float gA[4][32];
    __shared__ float cdA[4][32];

    const int tid  = threadIdx.x;
    const int lane = tid & 63;
    const int wv   = tid >> 6;
    const int row  = blockIdx.x * 4 + wv;

    float ms[8];
#pragma unroll
    for (int s = 0; s < 8; ++s) ms[s] = (s < ns) ? Mst[(long)s * NROWS + row] : -INFINITY;
    float mstar = -INFINITY;
#pragma unroll
    for (int s = 0; s < 8; ++s) mstar = fmaxf(mstar, ms[s]);
    float wgt[8]; float L = 0.f;
#pragma unroll
    for (int s = 0; s < 8; ++s) {
        wgt[s] = (ms[s] == -INFINITY) ? 0.f : __expf(ms[s] - mstar);
        if (s < ns) L += Lst[(long)s * NROWS + row] * wgt[s];
    }

    const int d0 = lane * 4;
    float ctx[4] = {0.f, 0.f, 0.f, 0.f};
#pragma unroll
    for (int s = 0; s < 8; ++s) {
        if (s < ns) {
            H4 t; t.u = *(const uint2*)&Oh[((long)s * NROWS + row) * 288 + d0];
#pragma unroll
            for (int i = 0; i < 4; ++i) ctx[i] += wgt[s] * (float)t.h[i];
        }
    }

    float cls[4] = {0.f, 0.f, 0.f, 0.f};
    if (lane < 8) {
#pragma unroll
        for (int s = 0; s < 8; ++s) {
            if (s < ns) {
                H4 t; t.u = *(const uint2*)&Oh[((long)s * NROWS + row) * 288 + 256 + lane * 4];
#pragma unroll
                for (int i = 0; i < 4; ++i) cls[i] += wgt[s] * (float)t.h[i];
            }
        }
    }

    float g = (lane < 25) ? genlog[(long)row * 32 + lane] : -INFINITY;
    float mg = g;
#pragma unroll
    for (int off = 32; off >= 1; off >>= 1) mg = fmaxf(mg, __shfl_xor(mg, off, 64));
    float se = (lane < 25) ? __expf(g - mg) : 0.f;
#pragma unroll
    for (int off = 32; off >= 1; off >>= 1) se += __shfl_xor(se, off, 64);
    const float glsm = g - mg - logf(se);

    const float qgate = genlog[(long)row * 32 + 25];
    const float invL = 1.f / L;
    float part = 0.f;
#pragma unroll
    for (int i = 0; i < 4; ++i)
        part += ctx[i] * invL * Wcp[256 + d0 + i];
#pragma unroll
    for (int off = 32; off >= 1; off >>= 1) part += __shfl_xor(part, off, 64);
    const float logit = qgate + part + bcp[0];

    const float lscp  = logsig(logit);
    const float lsgen = logsig(-logit);
    const float logL  = logf(L);

    if (lane < 8) {
#pragma unroll
        for (int i = 0; i < 4; ++i)
            cdA[wv][lane * 4 + i] = (cls[i] > 0.f) ? (logf(cls[i]) - logL) : -INFINITY;
    }
    if (lane < 25) gA[wv][lane] = glsm;
    __syncthreads();

    if (lane < 25) {
        const float a  = lscp + cdA[wv][lane];
        const float bb = lsgen + gA[wv][lane];
        const float mx = fmaxf(a, bb);
        const float o  = (mx == -INFINITY) ? -INFINITY
                         : mx + log1pf(__expf(fminf(a, bb) - mx));
        outp[(long)row * 25 + lane] = o;
    }
}

// ---------------------------------------------------------------------------
extern "C" void kernel_launch(void* const* d_in, const int* in_sizes, int n_in,
                              void* d_out, int out_size, void* d_ws, size_t ws_size,
                              hipStream_t stream) {
    const float* q_head = (const float*)d_in[0];
    const float* q_tail = (const float*)d_in[1];
    const float* c_head = (const float*)d_in[2];
    const float* c_tail = (const float*)d_in[3];
    const int*   labels = (const int*)d_in[4];
    const float* maskp  = (const float*)d_in[5];
    const float* Wrel   = (const float*)d_in[6];
    const float* brel   = (const float*)d_in[7];
    const float* Wgen   = (const float*)d_in[8];
    const float* bgen   = (const float*)d_in[9];
    const float* Wcp    = (const float*)d_in[10];
    const float* bcp    = (const float*)d_in[11];

    auto need = [](long ns) -> long { return 39075840l + ns * 4784128l; };
    int ns = 8, nsh = 3;
    if ((long)ws_size < need(8)) { ns = 4; nsh = 2; }
    if ((long)ws_size < need(4)) { ns = 2; nsh = 1; }
    if ((long)ws_size < need(2)) { ns = 1; nsh = 0; }
    const int jtiles = 128 / ns;

    char* ws = (char*)d_ws;
    _Float16* Qf     = (_Float16*)(ws);                   //  4 MB
    _Float16* Cf     = (_Float16*)(ws + 4194304l);        // 16 MB
    _Float16* CfT    = (_Float16*)(ws + 20971520l);       // 16 MB
    _Float16* WT     = (_Float16*)(ws + 37748736l);       // 256 KB
    _Float16* GenB   = (_Float16*)(ws + 38010880l);       // 16 KB
    float*    genlog = (float*)   (ws + 38027264l);       //  1 MB
    unsigned short* Oh = (unsigned short*)(ws + 39075840l);  // ns*4.5 MB fp16
    float*    Mst    = (float*)   (ws + 39075840l + (long)ns * 4718592l);
    float*    Lst    = Mst + (long)ns * NROWS;

    hipLaunchKernelGGL(wprep_kernel, dim3(288), dim3(256), 0, stream,
                       Wrel, Wgen, Wcp, WT, GenB);
    hipLaunchKernelGGL(emb_kernel, dim3(640), dim3(256), 0, stream,
                       q_head, q_tail, c_head, c_tail, WT, brel, GenB, bgen,
                       Qf, Cf, CfT, genlog);
    hipLaunchKernelGGL(attn_kernel, dim3(16 * 8 * ns), dim3(256), 0, stream,
                       Qf, Cf, CfT, labels, maskp, Oh, Mst, Lst, jtiles, nsh);
    hipLaunchKernelGGL(final_kernel, dim3(NROWS / 4), dim3(256), 0, stream,
                       genlog, Oh, Mst, Lst, Wcp, bcp, (float*)d_out, ns);
}